// Round 7
// baseline (728.672 us; speedup 1.0000x reference)
//
#include <hip/hip_runtime.h>
#include <hip/hip_bf16.h>
#include <cstdint>
#include <cstddef>
#include <type_traits>

typedef _Float16 half8 __attribute__((ext_vector_type(8)));
typedef _Float16 half4v __attribute__((ext_vector_type(4)));
typedef float float4v __attribute__((ext_vector_type(4)));

// ---------------- fused prep: zero cnt/flag + weight convert/transpose ----------------
// Disjoint index ranges in one grid: [0,n) zeroes, [n, n+n1+2*n2) converts weights.

__global__ void k_prep(int* __restrict__ cnt, int* __restrict__ flag,
                       const float* __restrict__ W1, const float* __restrict__ Wg1,
                       const float* __restrict__ Wg2, _Float16* __restrict__ W1t,
                       _Float16* __restrict__ Wg1t, _Float16* __restrict__ Wg2t,
                       int n, int in_dim, int hid) {
  int idx = blockIdx.x * blockDim.x + threadIdx.x;
  if (idx < n) { cnt[idx] = 0; flag[idx] = 0; return; }
  int w = idx - n;
  int n1 = in_dim * hid;
  int n2 = hid * hid;
  if (w < n1) {
    int nn = w / in_dim, k = w - nn * in_dim;
    W1t[w] = (_Float16)W1[(size_t)k * hid + nn];
  } else if (w < n1 + n2) {
    int i2 = w - n1;
    int nn = i2 / hid, k = i2 - nn * hid;
    Wg1t[i2] = (_Float16)Wg1[(size_t)k * hid + nn];
  } else if (w < n1 + 2 * n2) {
    int i2 = w - n1 - n2;
    int nn = i2 / hid, k = i2 - nn * hid;
    Wg2t[i2] = (_Float16)Wg2[(size_t)k * hid + nn];
  }
}

// ---------------- fused count + S1 mark (one E pass) ----------------
// cnt[d]++ for every edge; flag S1 = batch nodes + sources of edges into batch.

__global__ void k_countmark(const int* __restrict__ src, const int* __restrict__ dst,
                            int* __restrict__ cnt, int* __restrict__ flag,
                            int E, int Batch) {
  int e = blockIdx.x * blockDim.x + threadIdx.x;
  if (e < E) {
    int d = dst[e];
    atomicAdd(&cnt[d], 1);
    if (d < Batch) flag[src[e]] = 1;
  }
  if (e < Batch) flag[e] = 1;
}

// ---------------- single-block dual scan + finalize + emit (replaces 6 kernels) -----
// 1024 threads, 49 contiguous elements each. Pass 1: chunk sums of cnt & flag.
// Block-exclusive-scan both. Pass 2: write rowp/cursor (excl prefix of cnt),
// dinv, compacted S1 list (excl prefix of flag), s1cnt, rowp[n]=E.

__global__ __launch_bounds__(1024) void k_scanall(const int* __restrict__ cnt,
                                                  const int* __restrict__ flag,
                                                  int* __restrict__ rowp,
                                                  int* __restrict__ cursor,
                                                  float* __restrict__ dinv,
                                                  int* __restrict__ list,
                                                  int* __restrict__ s1cnt,
                                                  int n, int E) {
  __shared__ int smc[1024];
  __shared__ int smf[1024];
  const int tid = threadIdx.x;
  const int CPN = (n + 1023) >> 10;
  const int base = tid * CPN;
  int sc = 0, sf = 0;
  for (int j = 0; j < CPN; ++j) {
    int i = base + j;
    if (i < n) { sc += cnt[i]; sf += flag[i]; }
  }
  smc[tid] = sc;
  smf[tid] = sf;
  __syncthreads();
  for (int off = 1; off < 1024; off <<= 1) {
    int tc_ = (tid >= off) ? smc[tid - off] : 0;
    int tf_ = (tid >= off) ? smf[tid - off] : 0;
    __syncthreads();
    smc[tid] += tc_;
    smf[tid] += tf_;
    __syncthreads();
  }
  int rc = smc[tid] - sc;   // exclusive chunk base (cnt)
  int rf = smf[tid] - sf;   // exclusive chunk base (flag)
  for (int j = 0; j < CPN; ++j) {
    int i = base + j;
    if (i < n) {
      int c = cnt[i], f = flag[i];
      rowp[i] = rc;
      cursor[i] = rc;
      dinv[i] = rsqrtf((float)(c + 1));  // +1 self loop
      if (f) list[rf] = i;
      rc += c;
      rf += f;
    }
  }
  if (tid == 1023) { rowp[n] = E; s1cnt[0] = rf; }
}

__global__ void k_fill(const int* __restrict__ src, const int* __restrict__ dst,
                       int* __restrict__ cursor, int* __restrict__ csr_src, int E) {
  int e = blockIdx.x * blockDim.x + threadIdx.x;
  if (e < E) {
    int pos = atomicAdd(&cursor[dst[e]], 1);
    csr_src[pos] = src[e];
  }
}

// ---------------- fp16 MFMA GEMM, 256x256 tile, counted-vmcnt 3-buffer pipeline ----
// (harness-verified rounds 3/5/6; byte-identical here)

__device__ __forceinline__ void gl_lds16(const void* g, void* l) {
  __builtin_amdgcn_global_load_lds(
      (const __attribute__((address_space(1))) void*)g,
      (__attribute__((address_space(3))) void*)l, 16, 0, 0);
}

#define VMCNT(n) asm volatile("s_waitcnt vmcnt(" #n ")" ::: "memory")

template <int RA>
__device__ __forceinline__ void dma_tile(const char* const (&aS)[RA], const int (&aD)[RA],
                                         const char* const (&bS)[2], const int (&bD)[2],
                                         char* ab, char* bb, size_t advA, size_t advB) {
#pragma unroll
  for (int rr = 0; rr < RA; ++rr) gl_lds16(aS[rr] + advA, ab + aD[rr]);
#pragma unroll
  for (int rr = 0; rr < 2; ++rr) gl_lds16(bS[rr] + advB, bb + bD[rr]);
}

template <typename AT, int RELU, int BIAS, int SCALE, int GATHER>
__global__ __launch_bounds__(512) void k_gemm_mfma(const AT* __restrict__ A,
                                                   const _Float16* __restrict__ Bt,
                                                   const float* __restrict__ bias,
                                                   const float* __restrict__ rowscale,
                                                   _Float16* __restrict__ out,
                                                   int M, int N, int K,
                                                   const int* __restrict__ ridx,
                                                   const int* __restrict__ rcnt) {
  __shared__ alignas(16) AT Asm[3][256 * 32];
  __shared__ alignas(16) _Float16 Bsm[3][256 * 32];
  constexpr bool AF32 = std::is_same_v<AT, float>;
  constexpr int RA = AF32 ? 4 : 2;                   // A DMA rounds (8KB each)
  constexpr int ABUFB = 256 * 32 * (int)sizeof(AT);  // 32KB / 16KB
  constexpr int BBUFB = 256 * 32 * 2;                // 16KB

  const int tid = threadIdx.x;
  const int wv = tid >> 6;          // 0..7
  const int ln = tid & 63;
  const int quad = ln >> 4;
  const int l15 = ln & 15;
  const int wm = (wv >> 2) * 128;   // 0 or 128
  const int wn = (wv & 3) * 64;     // 0,64,128,192

  const int bm = (int)blockIdx.x * 256;

  int Meff = M;
  if constexpr (GATHER) {
    Meff = rcnt[0];
    if (bm >= Meff) return;         // uniform per block, before any barrier
  }

  // ---- per-thread DMA source precompute (dest linear; source pre-permuted) ----
  const char* aSrcB[RA];
  int aDstOff[RA];
#pragma unroll
  for (int rr = 0; rr < RA; ++rr) {
    int q = rr * 8192 + wv * 1024 + ln * 16;  // byte pos in A buf
    int row, colE;                            // colE in elements
    if constexpr (AF32) {
      int h = q >> 14;                        // half-buffer (cols 0-15 | 16-31)
      row = (q >> 6) & 255;
      colE = ((q & 63) >> 2) + (h << 4);
    } else {
      row = q >> 6;
      colE = (q & 63) >> 1;
    }
    int li = bm + row; if (li > Meff - 1) li = Meff - 1;  // clamp; epilogue masks
    int grow;
    if constexpr (GATHER) grow = ridx[li]; else grow = li;
    aSrcB[rr] = (const char*)(A + (size_t)grow * K + colE);
    aDstOff[rr] = rr * 8192 + wv * 1024;      // wave-uniform (lane*16 added by HW)
  }
  const char* bSrcB[2];
  int bDstOff[2];
#pragma unroll
  for (int rr = 0; rr < 2; ++rr) {
    int q = rr * 8192 + wv * 1024 + ln * 16;  // byte pos in B buf
    int row = q >> 6;
    int colH = (q & 63) >> 1;
    bSrcB[rr] = (const char*)(Bt + (size_t)row * K + colH);
    bDstOff[rr] = rr * 8192 + wv * 1024;
  }

  float4v acc[8][4];
#pragma unroll
  for (int i = 0; i < 8; ++i)
#pragma unroll
    for (int j = 0; j < 4; ++j) acc[i][j] = (float4v){0.f, 0.f, 0.f, 0.f};

  const int nk = K >> 5;   // >= 8 always here

  char* const Ab0 = (char*)&Asm[0][0];
  char* const Bb0 = (char*)&Bsm[0][0];

  // prologue: DMA tile 0 -> buf 0, tile 1 -> buf 1 (2*IPT outstanding)
  dma_tile<RA>(aSrcB, aDstOff, bSrcB, bDstOff, Ab0, Bb0, 0, 0);
  dma_tile<RA>(aSrcB, aDstOff, bSrcB, bDstOff, Ab0 + ABUFB, Bb0 + BBUFB,
               (size_t)32 * sizeof(AT), 64);

  int c0 = 0;  // buffer holding tile kt
  for (int kt = 0; kt < nk; ++kt) {
    // wait: tile kt resident (leave tile kt+1's IPT newest in flight)
    if (kt + 1 < nk) {
      if constexpr (AF32) { VMCNT(6); } else { VMCNT(4); }
    } else {
      VMCNT(0);
    }
    __builtin_amdgcn_sched_barrier(0);
    __builtin_amdgcn_s_barrier();       // publish all waves' tile-kt DMA
    __builtin_amdgcn_sched_barrier(0);

    // issue tile kt+2 DMA into the buffer last read at tile kt-1
    if (kt + 2 < nk) {
      int c2 = c0 + 2; if (c2 >= 3) c2 -= 3;
      dma_tile<RA>(aSrcB, aDstOff, bSrcB, bDstOff,
                   Ab0 + (size_t)c2 * ABUFB, Bb0 + (size_t)c2 * BBUFB,
                   (size_t)(kt + 2) * 32 * sizeof(AT), (size_t)(kt + 2) * 64);
      __builtin_amdgcn_sched_barrier(0);  // keep DMA issue ahead of ds_reads
    }

    // compute tile kt from buffer c0
    const AT* Ab = &Asm[c0][0];
    const _Float16* Bb = &Bsm[c0][0];
    half8 bf[4];
#pragma unroll
    for (int j = 0; j < 4; ++j)
      bf[j] = *(const half8*)(Bb + (wn + j * 16 + l15) * 32 + quad * 8);
#pragma unroll
    for (int i = 0; i < 8; ++i) {
      int rowa = wm + i * 16 + l15;
      half8 af;
      if constexpr (AF32) {
        // split-half: cols quad*8..quad*8+7 live in half (quad>>1), sub (quad&1)
        const float* ap = Ab + (quad >> 1) * 4096 + rowa * 16 + (quad & 1) * 8;
        float4v f0 = *(const float4v*)ap;
        float4v f1 = *(const float4v*)(ap + 4);
        af[0] = (_Float16)f0[0]; af[1] = (_Float16)f0[1];
        af[2] = (_Float16)f0[2]; af[3] = (_Float16)f0[3];
        af[4] = (_Float16)f1[0]; af[5] = (_Float16)f1[1];
        af[6] = (_Float16)f1[2]; af[7] = (_Float16)f1[3];
      } else {
        af = *(const half8*)(Ab + rowa * 32 + quad * 8);
      }
#pragma unroll
      for (int j = 0; j < 4; ++j)
        acc[i][j] = __builtin_amdgcn_mfma_f32_16x16x32_f16(af, bf[j], acc[i][j], 0, 0, 0);
    }

    c0 = (c0 == 2) ? 0 : c0 + 1;
  }

  // epilogue: C/D layout col=lane&15, row=quad*4+reg
#pragma unroll
  for (int j = 0; j < 4; ++j) {
    int c = wn + j * 16 + l15;
    float bv = BIAS ? bias[c] : 0.f;
#pragma unroll
    for (int i = 0; i < 8; ++i) {
      int rbase = bm + wm + i * 16 + quad * 4;
      float4v a = acc[i][j];
#pragma unroll
      for (int reg = 0; reg < 4; ++reg) {
        int r = rbase + reg;
        if (r < Meff) {
          int orow;
          if constexpr (GATHER) orow = ridx[r]; else orow = r;
          float v = a[reg] + bv;
          if (RELU) v = fmaxf(v, 0.f);
          if (SCALE) v *= rowscale[orow];
          out[(size_t)orow * N + c] = (_Float16)v;
        }
      }
    }
  }
}

// ---------------- GCN aggregation (gather, one wave/node, 256 feats) ----------------
// t is PRE-SCALED: t'[i] = t[i]*dinv[i].  out[i] = (t'[i] + sum t'[src]) * dinv[i] + b

template <typename OT>
__global__ __launch_bounds__(256) void k_agg(const _Float16* __restrict__ t,
                                             const int* __restrict__ row_ptr,
                                             const int* __restrict__ csr_src,
                                             const float* __restrict__ dinv,
                                             const float* __restrict__ bias,
                                             OT* __restrict__ out, int n_nodes) {
  int w = (int)((blockIdx.x * 256 + threadIdx.x) >> 6);
  int lane = threadIdx.x & 63;
  if (w >= n_nodes) return;
  float di = dinv[w];
  half4v v = *(const half4v*)(t + (size_t)w * 256 + lane * 4);
  float ax = (float)v[0], ay = (float)v[1], az = (float)v[2], aw = (float)v[3];
  int e0 = row_ptr[w], e1 = row_ptr[w + 1];
  int e = e0;
  for (; e + 4 <= e1; e += 4) {
    int s0 = csr_src[e];
    int s1 = csr_src[e + 1];
    int s2 = csr_src[e + 2];
    int s3 = csr_src[e + 3];
    half4v u0 = *(const half4v*)(t + (size_t)s0 * 256 + lane * 4);
    half4v u1 = *(const half4v*)(t + (size_t)s1 * 256 + lane * 4);
    half4v u2 = *(const half4v*)(t + (size_t)s2 * 256 + lane * 4);
    half4v u3 = *(const half4v*)(t + (size_t)s3 * 256 + lane * 4);
    ax += (float)u0[0] + (float)u1[0] + (float)u2[0] + (float)u3[0];
    ay += (float)u0[1] + (float)u1[1] + (float)u2[1] + (float)u3[1];
    az += (float)u0[2] + (float)u1[2] + (float)u2[2] + (float)u3[2];
    aw += (float)u0[3] + (float)u1[3] + (float)u2[3] + (float)u3[3];
  }
  for (; e < e1; ++e) {
    int s = csr_src[e];
    half4v u = *(const half4v*)(t + (size_t)s * 256 + lane * 4);
    ax += (float)u[0]; ay += (float)u[1]; az += (float)u[2]; aw += (float)u[3];
  }
  const float4 b = ((const float4*)bias)[lane];
  if constexpr (std::is_same_v<OT, float>) {
    float4 o;
    o.x = ax * di + b.x; o.y = ay * di + b.y;
    o.z = az * di + b.z; o.w = aw * di + b.w;
    ((float4*)(out + (size_t)w * 256))[lane] = o;
  } else {
    half4v o;
    o[0] = (_Float16)(ax * di + b.x); o[1] = (_Float16)(ay * di + b.y);
    o[2] = (_Float16)(az * di + b.z); o[3] = (_Float16)(aw * di + b.w);
    *(half4v*)(out + (size_t)w * 256 + lane * 4) = o;
  }
}

// list-driven variant: only nodes in list[0..s1cnt) are aggregated (S1 pruning).
__global__ __launch_bounds__(256) void k_agg_g(const _Float16* __restrict__ t,
                                               const int* __restrict__ row_ptr,
                                               const int* __restrict__ csr_src,
                                               const float* __restrict__ dinv,
                                               const float* __restrict__ bias,
                                               _Float16* __restrict__ out,
                                               const int* __restrict__ list,
                                               const int* __restrict__ s1cnt) {
  int wi = (int)((blockIdx.x * 256 + threadIdx.x) >> 6);
  int lane = threadIdx.x & 63;
  if (wi >= s1cnt[0]) return;      // per-wave uniform; no barriers in kernel
  int w = list[wi];
  float di = dinv[w];
  half4v v = *(const half4v*)(t + (size_t)w * 256 + lane * 4);
  float ax = (float)v[0], ay = (float)v[1], az = (float)v[2], aw = (float)v[3];
  int e0 = row_ptr[w], e1 = row_ptr[w + 1];
  int e = e0;
  for (; e + 4 <= e1; e += 4) {
    int s0 = csr_src[e];
    int s1 = csr_src[e + 1];
    int s2 = csr_src[e + 2];
    int s3 = csr_src[e + 3];
    half4v u0 = *(const half4v*)(t + (size_t)s0 * 256 + lane * 4);
    half4v u1 = *(const half4v*)(t + (size_t)s1 * 256 + lane * 4);
    half4v u2 = *(const half4v*)(t + (size_t)s2 * 256 + lane * 4);
    half4v u3 = *(const half4v*)(t + (size_t)s3 * 256 + lane * 4);
    ax += (float)u0[0] + (float)u1[0] + (float)u2[0] + (float)u3[0];
    ay += (float)u0[1] + (float)u1[1] + (float)u2[1] + (float)u3[1];
    az += (float)u0[2] + (float)u1[2] + (float)u2[2] + (float)u3[2];
    aw += (float)u0[3] + (float)u1[3] + (float)u2[3] + (float)u3[3];
  }
  for (; e < e1; ++e) {
    int s = csr_src[e];
    half4v u = *(const half4v*)(t + (size_t)s * 256 + lane * 4);
    ax += (float)u[0]; ay += (float)u[1]; az += (float)u[2]; aw += (float)u[3];
  }
  const float4 b = ((const float4*)bias)[lane];
  half4v o;
  o[0] = (_Float16)(ax * di + b.x); o[1] = (_Float16)(ay * di + b.y);
  o[2] = (_Float16)(az * di + b.z); o[3] = (_Float16)(aw * di + b.w);
  *(half4v*)(out + (size_t)w * 256 + lane * 4) = o;
}

// ---------------- fused tail: logits = (relu(agg2 @ W2 + b2)) @ Wc + bc ------------
// One dispatch replacing k_gemm + k_cls (and the h3 buffer). 256 thr, 64 rows/block.
// Each thread computes a 4x8 h3 sub-tile (cols tc..tc+7 of N=128), applies
// relu+bias, reduces against Wc in-register, then LDS cross-thread reduce.

__global__ __launch_bounds__(256) void k_tail(const float* __restrict__ A,
                                              const float* __restrict__ B,
                                              const float* __restrict__ b2,
                                              const float* __restrict__ Wc,
                                              const float* __restrict__ bc,
                                              float* __restrict__ out,
                                              int M, int N, int K) {
  __shared__ float As[16][68];
  __shared__ float Bs[16][136];
  __shared__ float wsm[256];          // Wc: [N][2], N=128
  __shared__ float red[64][16][2];
  const int bm = blockIdx.x * 64;
  const int tid = threadIdx.x;
  const int tr = (tid >> 4) << 2;     // 0..60
  const int tc = (tid & 15) << 3;     // 0..120
  const int lm  = tid >> 2;           // A stage row 0..63
  const int lk  = (tid & 3) << 2;     // A stage k 0,4,8,12
  const int lk2 = tid >> 4;           // B stage k 0..15
  const int ln  = (tid & 15) << 3;    // B stage col 0..120
  wsm[tid] = Wc[tid];
  const bool arow_ok = (bm + lm) < M;
  const float* Aptr = A + (size_t)(bm + lm) * K + lk;
  const float* Bptr = B + (size_t)lk2 * N + ln;
  float acc[4][8] = {};
  for (int k0 = 0; k0 < K; k0 += 16) {
    float4 a4 = make_float4(0.f, 0.f, 0.f, 0.f);
    if (arow_ok) a4 = *(const float4*)(Aptr + k0);
    float4 b4 = *(const float4*)(Bptr + (size_t)k0 * N);
    float4 b5 = *(const float4*)(Bptr + (size_t)k0 * N + 4);
    As[lk + 0][lm] = a4.x;
    As[lk + 1][lm] = a4.y;
    As[lk + 2][lm] = a4.z;
    As[lk + 3][lm] = a4.w;
    *(float4*)&Bs[lk2][ln] = b4;
    *(float4*)&Bs[lk2][ln + 4] = b5;
    __syncthreads();
#pragma unroll
    for (int k = 0; k < 16; ++k) {
      float4 av = *(const float4*)&As[k][tr];
      float a[4] = {av.x, av.y, av.z, av.w};
      float b[8];
      *(float4*)&b[0] = *(const float4*)&Bs[k][tc];
      *(float4*)&b[4] = *(const float4*)&Bs[k][tc + 4];
#pragma unroll
      for (int i = 0; i < 4; ++i)
#pragma unroll
        for (int j = 0; j < 8; ++j) acc[i][j] += a[i] * b[j];
    }
    __syncthreads();
  }
  // relu + b2, then partial logits vs Wc
  float p[4][2] = {};
#pragma unroll
  for (int j = 0; j < 8; ++j) {
    float bb = b2[tc + j];
    float w0 = wsm[(tc + j) * 2 + 0];
    float w1 = wsm[(tc + j) * 2 + 1];
#pragma unroll
    for (int i = 0; i < 4; ++i) {
      float v = fmaxf(acc[i][j] + bb, 0.f);
      p[i][0] += v * w0;
      p[i][1] += v * w1;
    }
  }
#pragma unroll
  for (int i = 0; i < 4; ++i) {
    red[tr + i][tid & 15][0] = p[i][0];
    red[tr + i][tid & 15][1] = p[i][1];
  }
  __syncthreads();
  if (tid < 128) {
    int row = tid >> 1, kk = tid & 1;
    float s = 0.f;
#pragma unroll
    for (int t = 0; t < 16; ++t) s += red[row][t][kk];
    int r = bm + row;
    if (r < M) out[2 * r + kk] = s + bc[kk];
  }
}

// ---------------- launch ----------------

extern "C" void kernel_launch(void* const* d_in, const int* in_sizes, int n_in,
                              void* d_out, int out_size, void* d_ws, size_t ws_size,
                              hipStream_t stream) {
  const float* x   = (const float*)d_in[0];
  const int*   ei  = (const int*)d_in[1];
  const float* W1  = (const float*)d_in[2];
  const float* b1  = (const float*)d_in[3];
  const float* Wg1 = (const float*)d_in[4];
  const float* bg1 = (const float*)d_in[5];
  const float* Wg2 = (const float*)d_in[6];
  const float* bg2 = (const float*)d_in[7];
  const float* W2  = (const float*)d_in[8];
  const float* b2  = (const float*)d_in[9];
  const float* Wc  = (const float*)d_in[10];
  const float* bc  = (const float*)d_in[11];
  float* out = (float*)d_out;

  const int hid     = in_sizes[3];            // 256
  const int in_dim  = in_sizes[2] / hid;      // 768
  const int out_dim = in_sizes[9];            // 128
  const int N       = in_sizes[0] / in_dim;   // 50000
  const int E       = in_sizes[1] / 2;        // 800000
  const int Batch   = out_size / 2;           // 1024

  const int* srcI = ei;
  const int* dstI = ei + E;

  char* ws = (char*)d_ws;
  size_t off = 0;
  auto alloc = [&](size_t bytes) -> void* {
    void* p = ws + off;
    off = (off + bytes + 255) & ~(size_t)255;
    return p;
  };
  _Float16* h0h  = (_Float16*)alloc((size_t)N * hid * 2);
  _Float16* t1h  = (_Float16*)alloc((size_t)N * hid * 2);   // pre-scaled by dinv
  _Float16* h1h  = (_Float16*)alloc((size_t)N * hid * 2);   // only S1 rows valid
  _Float16* t2h  = (_Float16*)alloc((size_t)N * hid * 2);   // only S1 rows valid
  _Float16* W1t  = (_Float16*)alloc((size_t)in_dim * hid * 2);
  _Float16* Wg1t = (_Float16*)alloc((size_t)hid * hid * 2);
  _Float16* Wg2t = (_Float16*)alloc((size_t)hid * hid * 2);
  float* agg2    = (float*)alloc((size_t)Batch * hid * 4);
  float* dinv    = (float*)alloc((size_t)N * 4);
  int*   cnt     = (int*)alloc((size_t)N * 4);
  int*   rowp    = (int*)alloc((size_t)(N + 1) * 4);
  int*   cursor  = (int*)alloc((size_t)N * 4);
  int*   csrs    = (int*)alloc((size_t)E * 4);
  int*   flag    = (int*)alloc((size_t)N * 4);
  int*   list    = (int*)alloc((size_t)N * 4);
  int*   s1cnt   = (int*)alloc((size_t)64);
  (void)ws_size; (void)n_in;

  dim3 blk(256);

  // 1) zero + weight convert (fused)
  {
    int total = N + in_dim * hid + 2 * hid * hid;
    k_prep<<<(total + 255) / 256, blk, 0, stream>>>(cnt, flag, W1, Wg1, Wg2,
                                                    W1t, Wg1t, Wg2t, N, in_dim, hid);
  }
  // 2) count + S1 mark (fused E pass)
  k_countmark<<<(E + 255) / 256, blk, 0, stream>>>(srcI, dstI, cnt, flag, E, Batch);
  // 3) dual scan + finalize + emit (single block)
  k_scanall<<<1, 1024, 0, stream>>>(cnt, flag, rowp, cursor, dinv, list, s1cnt, N, E);
  // 4) CSR fill
  k_fill<<<(E + 255) / 256, blk, 0, stream>>>(srcI, dstI, cursor, csrs, E);

  const int ng = (N + 255) / 256;   // 196 blocks, full-N output tile
  dim3 gblk(512);
  // 5) h0 = relu(x @ W1 + b1)
  k_gemm_mfma<float, 1, 1, 0, 0><<<dim3(ng), gblk, 0, stream>>>(x, W1t, b1, nullptr, h0h, N, hid, in_dim, nullptr, nullptr);
  // 6) t1' = (h0 @ Wg1) * dinv[row]   (all nodes)
  k_gemm_mfma<_Float16, 0, 0, 1, 0><<<dim3(ng), gblk, 0, stream>>>(h0h, Wg1t, nullptr, dinv, t1h, N, hid, hid, nullptr, nullptr);
  // 7) h1 = (t1'[i] + sum t1'[src]) * dinv[i] + bg1   -- S1 nodes only
  k_agg_g<<<(N + 3) / 4, blk, 0, stream>>>(t1h, rowp, csrs, dinv, bg1, h1h, list, s1cnt);
  // 8) t2' = (h1 @ Wg2) * dinv[row]   -- gather over S1 rows
  k_gemm_mfma<_Float16, 0, 0, 1, 1><<<dim3(ng), gblk, 0, stream>>>(h1h, Wg2t, nullptr, dinv, t2h, N, hid, hid, list, s1cnt);
  // 9) conv2 aggregation for rows [0, Batch) (fp32 out)
  k_agg<float><<<(Batch + 3) / 4, blk, 0, stream>>>(t2h, rowp, csrs, dinv, bg2, agg2, Batch);
  // 10) logits = relu(agg2 @ W2 + b2) @ Wc + bc   (fused tail)
  k_tail<<<(Batch + 63) / 64, blk, 0, stream>>>(agg2, W2, b2, Wc, bc, out, Batch, out_dim, hid);
}

// Round 8
// 522.839 us; speedup vs baseline: 1.3937x; 1.3937x over previous
//
#include <hip/hip_runtime.h>
#include <hip/hip_bf16.h>
#include <cstdint>
#include <cstddef>
#include <type_traits>

typedef _Float16 half8 __attribute__((ext_vector_type(8)));
typedef _Float16 half4v __attribute__((ext_vector_type(4)));
typedef float float4v __attribute__((ext_vector_type(4)));

// ---------------- fused prep: zero cnt/flag + weight convert/transpose ----------------

__global__ void k_prep(int* __restrict__ cnt, int* __restrict__ flag,
                       const float* __restrict__ W1, const float* __restrict__ Wg1,
                       const float* __restrict__ Wg2, _Float16* __restrict__ W1t,
                       _Float16* __restrict__ Wg1t, _Float16* __restrict__ Wg2t,
                       int n, int in_dim, int hid) {
  int idx = blockIdx.x * blockDim.x + threadIdx.x;
  if (idx < n) { cnt[idx] = 0; flag[idx] = 0; return; }
  int w = idx - n;
  int n1 = in_dim * hid;
  int n2 = hid * hid;
  if (w < n1) {
    int nn = w / in_dim, k = w - nn * in_dim;
    W1t[w] = (_Float16)W1[(size_t)k * hid + nn];
  } else if (w < n1 + n2) {
    int i2 = w - n1;
    int nn = i2 / hid, k = i2 - nn * hid;
    Wg1t[i2] = (_Float16)Wg1[(size_t)k * hid + nn];
  } else if (w < n1 + 2 * n2) {
    int i2 = w - n1 - n2;
    int nn = i2 / hid, k = i2 - nn * hid;
    Wg2t[i2] = (_Float16)Wg2[(size_t)k * hid + nn];
  }
}

// ---------------- fused count + S1 mark (one E pass) ----------------

__global__ void k_countmark(const int* __restrict__ src, const int* __restrict__ dst,
                            int* __restrict__ cnt, int* __restrict__ flag,
                            int E, int Batch) {
  int e = blockIdx.x * blockDim.x + threadIdx.x;
  if (e < E) {
    int d = dst[e];
    atomicAdd(&cnt[d], 1);
    if (d < Batch) flag[src[e]] = 1;
  }
  if (e < Batch) flag[e] = 1;
}

// ---------------- hierarchical DUAL scan (cnt & flag in one pass) -------------------
// Round-7 post-mortem: single-block scan was 229us (1 CU, latency-bound). Back to
// the parallel 49-block structure, but dual-tracked and fused: 3 dispatches total.

__global__ __launch_bounds__(1024) void k_scan_local_dual(const int* __restrict__ cnt,
                                                          const int* __restrict__ flag,
                                                          int* __restrict__ rowp,
                                                          int* __restrict__ fidx,
                                                          int* __restrict__ bsumc,
                                                          int* __restrict__ bsumf, int n) {
  __shared__ int smc[1024];
  __shared__ int smf[1024];
  int tid = threadIdx.x;
  int i = blockIdx.x * 1024 + tid;
  int vc = (i < n) ? cnt[i] : 0;
  int vf = (i < n) ? flag[i] : 0;
  smc[tid] = vc;
  smf[tid] = vf;
  __syncthreads();
  for (int off = 1; off < 1024; off <<= 1) {
    int tc_ = (tid >= off) ? smc[tid - off] : 0;
    int tf_ = (tid >= off) ? smf[tid - off] : 0;
    __syncthreads();
    smc[tid] += tc_;
    smf[tid] += tf_;
    __syncthreads();
  }
  if (i < n) {
    rowp[i] = smc[tid] - vc;  // exclusive (pre-fixup)
    fidx[i] = smf[tid] - vf;
  }
  if (tid == 1023) { bsumc[blockIdx.x] = smc[1023]; bsumf[blockIdx.x] = smf[1023]; }
}

__global__ __launch_bounds__(1024) void k_scan_sums_dual(int* __restrict__ bsumc,
                                                         int* __restrict__ bsumf, int nb) {
  __shared__ int smc[1024];
  __shared__ int smf[1024];
  int tid = threadIdx.x;
  int vc = (tid < nb) ? bsumc[tid] : 0;
  int vf = (tid < nb) ? bsumf[tid] : 0;
  smc[tid] = vc;
  smf[tid] = vf;
  __syncthreads();
  for (int off = 1; off < 1024; off <<= 1) {
    int tc_ = (tid >= off) ? smc[tid - off] : 0;
    int tf_ = (tid >= off) ? smf[tid - off] : 0;
    __syncthreads();
    smc[tid] += tc_;
    smf[tid] += tf_;
    __syncthreads();
  }
  if (tid < nb) { bsumc[tid] = smc[tid] - vc; bsumf[tid] = smf[tid] - vf; }
}

// fixup + cursor + dinv + S1 list emit + s1cnt + rowp[n], fused
__global__ void k_finalize_all(int* __restrict__ rowp, int* __restrict__ fidx,
                               const int* __restrict__ bsumc, const int* __restrict__ bsumf,
                               const int* __restrict__ cnt, const int* __restrict__ flag,
                               int* __restrict__ cursor, float* __restrict__ dinv,
                               int* __restrict__ list, int* __restrict__ s1cnt,
                               int n, int E) {
  int i = blockIdx.x * blockDim.x + threadIdx.x;
  if (i < n) {
    int v = rowp[i] + bsumc[i >> 10];
    rowp[i] = v;
    cursor[i] = v;
    dinv[i] = rsqrtf((float)(cnt[i] + 1));  // +1 self loop
    int f = flag[i];
    int fp = fidx[i] + bsumf[i >> 10];
    if (f) list[fp] = i;
    if (i == n - 1) { s1cnt[0] = fp + f; rowp[n] = E; }
  }
}

__global__ void k_fill(const int* __restrict__ src, const int* __restrict__ dst,
                       int* __restrict__ cursor, int* __restrict__ csr_src, int E) {
  int e = blockIdx.x * blockDim.x + threadIdx.x;
  if (e < E) {
    int pos = atomicAdd(&cursor[dst[e]], 1);
    csr_src[pos] = src[e];
  }
}

// ---------------- fp16 MFMA GEMM, 256x256 tile, counted-vmcnt 3-buffer pipeline ----
// (harness-verified rounds 3/5/6/7; byte-identical here)

__device__ __forceinline__ void gl_lds16(const void* g, void* l) {
  __builtin_amdgcn_global_load_lds(
      (const __attribute__((address_space(1))) void*)g,
      (__attribute__((address_space(3))) void*)l, 16, 0, 0);
}

#define VMCNT(n) asm volatile("s_waitcnt vmcnt(" #n ")" ::: "memory")

template <int RA>
__device__ __forceinline__ void dma_tile(const char* const (&aS)[RA], const int (&aD)[RA],
                                         const char* const (&bS)[2], const int (&bD)[2],
                                         char* ab, char* bb, size_t advA, size_t advB) {
#pragma unroll
  for (int rr = 0; rr < RA; ++rr) gl_lds16(aS[rr] + advA, ab + aD[rr]);
#pragma unroll
  for (int rr = 0; rr < 2; ++rr) gl_lds16(bS[rr] + advB, bb + bD[rr]);
}

template <typename AT, int RELU, int BIAS, int SCALE, int GATHER>
__global__ __launch_bounds__(512) void k_gemm_mfma(const AT* __restrict__ A,
                                                   const _Float16* __restrict__ Bt,
                                                   const float* __restrict__ bias,
                                                   const float* __restrict__ rowscale,
                                                   _Float16* __restrict__ out,
                                                   int M, int N, int K,
                                                   const int* __restrict__ ridx,
                                                   const int* __restrict__ rcnt) {
  __shared__ alignas(16) AT Asm[3][256 * 32];
  __shared__ alignas(16) _Float16 Bsm[3][256 * 32];
  constexpr bool AF32 = std::is_same_v<AT, float>;
  constexpr int RA = AF32 ? 4 : 2;                   // A DMA rounds (8KB each)
  constexpr int ABUFB = 256 * 32 * (int)sizeof(AT);  // 32KB / 16KB
  constexpr int BBUFB = 256 * 32 * 2;                // 16KB

  const int tid = threadIdx.x;
  const int wv = tid >> 6;          // 0..7
  const int ln = tid & 63;
  const int quad = ln >> 4;
  const int l15 = ln & 15;
  const int wm = (wv >> 2) * 128;   // 0 or 128
  const int wn = (wv & 3) * 64;     // 0,64,128,192

  const int bm = (int)blockIdx.x * 256;

  int Meff = M;
  if constexpr (GATHER) {
    Meff = rcnt[0];
    if (bm >= Meff) return;         // uniform per block, before any barrier
  }

  // ---- per-thread DMA source precompute (dest linear; source pre-permuted) ----
  const char* aSrcB[RA];
  int aDstOff[RA];
#pragma unroll
  for (int rr = 0; rr < RA; ++rr) {
    int q = rr * 8192 + wv * 1024 + ln * 16;  // byte pos in A buf
    int row, colE;                            // colE in elements
    if constexpr (AF32) {
      int h = q >> 14;                        // half-buffer (cols 0-15 | 16-31)
      row = (q >> 6) & 255;
      colE = ((q & 63) >> 2) + (h << 4);
    } else {
      row = q >> 6;
      colE = (q & 63) >> 1;
    }
    int li = bm + row; if (li > Meff - 1) li = Meff - 1;  // clamp; epilogue masks
    int grow;
    if constexpr (GATHER) grow = ridx[li]; else grow = li;
    aSrcB[rr] = (const char*)(A + (size_t)grow * K + colE);
    aDstOff[rr] = rr * 8192 + wv * 1024;      // wave-uniform (lane*16 added by HW)
  }
  const char* bSrcB[2];
  int bDstOff[2];
#pragma unroll
  for (int rr = 0; rr < 2; ++rr) {
    int q = rr * 8192 + wv * 1024 + ln * 16;  // byte pos in B buf
    int row = q >> 6;
    int colH = (q & 63) >> 1;
    bSrcB[rr] = (const char*)(Bt + (size_t)row * K + colH);
    bDstOff[rr] = rr * 8192 + wv * 1024;
  }

  float4v acc[8][4];
#pragma unroll
  for (int i = 0; i < 8; ++i)
#pragma unroll
    for (int j = 0; j < 4; ++j) acc[i][j] = (float4v){0.f, 0.f, 0.f, 0.f};

  const int nk = K >> 5;   // >= 8 always here

  char* const Ab0 = (char*)&Asm[0][0];
  char* const Bb0 = (char*)&Bsm[0][0];

  // prologue: DMA tile 0 -> buf 0, tile 1 -> buf 1 (2*IPT outstanding)
  dma_tile<RA>(aSrcB, aDstOff, bSrcB, bDstOff, Ab0, Bb0, 0, 0);
  dma_tile<RA>(aSrcB, aDstOff, bSrcB, bDstOff, Ab0 + ABUFB, Bb0 + BBUFB,
               (size_t)32 * sizeof(AT), 64);

  int c0 = 0;  // buffer holding tile kt
  for (int kt = 0; kt < nk; ++kt) {
    // wait: tile kt resident (leave tile kt+1's IPT newest in flight)
    if (kt + 1 < nk) {
      if constexpr (AF32) { VMCNT(6); } else { VMCNT(4); }
    } else {
      VMCNT(0);
    }
    __builtin_amdgcn_sched_barrier(0);
    __builtin_amdgcn_s_barrier();       // publish all waves' tile-kt DMA
    __builtin_amdgcn_sched_barrier(0);

    // issue tile kt+2 DMA into the buffer last read at tile kt-1
    if (kt + 2 < nk) {
      int c2 = c0 + 2; if (c2 >= 3) c2 -= 3;
      dma_tile<RA>(aSrcB, aDstOff, bSrcB, bDstOff,
                   Ab0 + (size_t)c2 * ABUFB, Bb0 + (size_t)c2 * BBUFB,
                   (size_t)(kt + 2) * 32 * sizeof(AT), (size_t)(kt + 2) * 64);
      __builtin_amdgcn_sched_barrier(0);  // keep DMA issue ahead of ds_reads
    }

    // compute tile kt from buffer c0
    const AT* Ab = &Asm[c0][0];
    const _Float16* Bb = &Bsm[c0][0];
    half8 bf[4];
#pragma unroll
    for (int j = 0; j < 4; ++j)
      bf[j] = *(const half8*)(Bb + (wn + j * 16 + l15) * 32 + quad * 8);
#pragma unroll
    for (int i = 0; i < 8; ++i) {
      int rowa = wm + i * 16 + l15;
      half8 af;
      if constexpr (AF32) {
        // split-half: cols quad*8..quad*8+7 live in half (quad>>1), sub (quad&1)
        const float* ap = Ab + (quad >> 1) * 4096 + rowa * 16 + (quad & 1) * 8;
        float4v f0 = *(const float4v*)ap;
        float4v f1 = *(const float4v*)(ap + 4);
        af[0] = (_Float16)f0[0]; af[1] = (_Float16)f0[1];
        af[2] = (_Float16)f0[2]; af[3] = (_Float16)f0[3];
        af[4] = (_Float16)f1[0]; af[5] = (_Float16)f1[1];
        af[6] = (_Float16)f1[2]; af[7] = (_Float16)f1[3];
      } else {
        af = *(const half8*)(Ab + rowa * 32 + quad * 8);
      }
#pragma unroll
      for (int j = 0; j < 4; ++j)
        acc[i][j] = __builtin_amdgcn_mfma_f32_16x16x32_f16(af, bf[j], acc[i][j], 0, 0, 0);
    }

    c0 = (c0 == 2) ? 0 : c0 + 1;
  }

  // epilogue: C/D layout col=lane&15, row=quad*4+reg
#pragma unroll
  for (int j = 0; j < 4; ++j) {
    int c = wn + j * 16 + l15;
    float bv = BIAS ? bias[c] : 0.f;
#pragma unroll
    for (int i = 0; i < 8; ++i) {
      int rbase = bm + wm + i * 16 + quad * 4;
      float4v a = acc[i][j];
#pragma unroll
      for (int reg = 0; reg < 4; ++reg) {
        int r = rbase + reg;
        if (r < Meff) {
          int orow;
          if constexpr (GATHER) orow = ridx[r]; else orow = r;
          float v = a[reg] + bv;
          if (RELU) v = fmaxf(v, 0.f);
          if (SCALE) v *= rowscale[orow];
          out[(size_t)orow * N + c] = (_Float16)v;
        }
      }
    }
  }
}

// ---------------- GCN aggregation (gather, one wave/node, 256 feats) ----------------
// t is PRE-SCALED: t'[i] = t[i]*dinv[i].  out[i] = (t'[i] + sum t'[src]) * dinv[i] + b

template <typename OT>
__global__ __launch_bounds__(256) void k_agg(const _Float16* __restrict__ t,
                                             const int* __restrict__ row_ptr,
                                             const int* __restrict__ csr_src,
                                             const float* __restrict__ dinv,
                                             const float* __restrict__ bias,
                                             OT* __restrict__ out, int n_nodes) {
  int w = (int)((blockIdx.x * 256 + threadIdx.x) >> 6);
  int lane = threadIdx.x & 63;
  if (w >= n_nodes) return;
  float di = dinv[w];
  half4v v = *(const half4v*)(t + (size_t)w * 256 + lane * 4);
  float ax = (float)v[0], ay = (float)v[1], az = (float)v[2], aw = (float)v[3];
  int e0 = row_ptr[w], e1 = row_ptr[w + 1];
  int e = e0;
  for (; e + 4 <= e1; e += 4) {
    int s0 = csr_src[e];
    int s1 = csr_src[e + 1];
    int s2 = csr_src[e + 2];
    int s3 = csr_src[e + 3];
    half4v u0 = *(const half4v*)(t + (size_t)s0 * 256 + lane * 4);
    half4v u1 = *(const half4v*)(t + (size_t)s1 * 256 + lane * 4);
    half4v u2 = *(const half4v*)(t + (size_t)s2 * 256 + lane * 4);
    half4v u3 = *(const half4v*)(t + (size_t)s3 * 256 + lane * 4);
    ax += (float)u0[0] + (float)u1[0] + (float)u2[0] + (float)u3[0];
    ay += (float)u0[1] + (float)u1[1] + (float)u2[1] + (float)u3[1];
    az += (float)u0[2] + (float)u1[2] + (float)u2[2] + (float)u3[2];
    aw += (float)u0[3] + (float)u1[3] + (float)u2[3] + (float)u3[3];
  }
  for (; e < e1; ++e) {
    int s = csr_src[e];
    half4v u = *(const half4v*)(t + (size_t)s * 256 + lane * 4);
    ax += (float)u[0]; ay += (float)u[1]; az += (float)u[2]; aw += (float)u[3];
  }
  const float4 b = ((const float4*)bias)[lane];
  if constexpr (std::is_same_v<OT, float>) {
    float4 o;
    o.x = ax * di + b.x; o.y = ay * di + b.y;
    o.z = az * di + b.z; o.w = aw * di + b.w;
    ((float4*)(out + (size_t)w * 256))[lane] = o;
  } else {
    half4v o;
    o[0] = (_Float16)(ax * di + b.x); o[1] = (_Float16)(ay * di + b.y);
    o[2] = (_Float16)(az * di + b.z); o[3] = (_Float16)(aw * di + b.w);
    *(half4v*)(out + (size_t)w * 256 + lane * 4) = o;
  }
}

// list-driven variant: only nodes in list[0..s1cnt) are aggregated (S1 pruning).
__global__ __launch_bounds__(256) void k_agg_g(const _Float16* __restrict__ t,
                                               const int* __restrict__ row_ptr,
                                               const int* __restrict__ csr_src,
                                               const float* __restrict__ dinv,
                                               const float* __restrict__ bias,
                                               _Float16* __restrict__ out,
                                               const int* __restrict__ list,
                                               const int* __restrict__ s1cnt) {
  int wi = (int)((blockIdx.x * 256 + threadIdx.x) >> 6);
  int lane = threadIdx.x & 63;
  if (wi >= s1cnt[0]) return;      // per-wave uniform; no barriers in kernel
  int w = list[wi];
  float di = dinv[w];
  half4v v = *(const half4v*)(t + (size_t)w * 256 + lane * 4);
  float ax = (float)v[0], ay = (float)v[1], az = (float)v[2], aw = (float)v[3];
  int e0 = row_ptr[w], e1 = row_ptr[w + 1];
  int e = e0;
  for (; e + 4 <= e1; e += 4) {
    int s0 = csr_src[e];
    int s1 = csr_src[e + 1];
    int s2 = csr_src[e + 2];
    int s3 = csr_src[e + 3];
    half4v u0 = *(const half4v*)(t + (size_t)s0 * 256 + lane * 4);
    half4v u1 = *(const half4v*)(t + (size_t)s1 * 256 + lane * 4);
    half4v u2 = *(const half4v*)(t + (size_t)s2 * 256 + lane * 4);
    half4v u3 = *(const half4v*)(t + (size_t)s3 * 256 + lane * 4);
    ax += (float)u0[0] + (float)u1[0] + (float)u2[0] + (float)u3[0];
    ay += (float)u0[1] + (float)u1[1] + (float)u2[1] + (float)u3[1];
    az += (float)u0[2] + (float)u1[2] + (float)u2[2] + (float)u3[2];
    aw += (float)u0[3] + (float)u1[3] + (float)u2[3] + (float)u3[3];
  }
  for (; e < e1; ++e) {
    int s = csr_src[e];
    half4v u = *(const half4v*)(t + (size_t)s * 256 + lane * 4);
    ax += (float)u[0]; ay += (float)u[1]; az += (float)u[2]; aw += (float)u[3];
  }
  const float4 b = ((const float4*)bias)[lane];
  half4v o;
  o[0] = (_Float16)(ax * di + b.x); o[1] = (_Float16)(ay * di + b.y);
  o[2] = (_Float16)(az * di + b.z); o[3] = (_Float16)(aw * di + b.w);
  *(half4v*)(out + (size_t)w * 256 + lane * 4) = o;
}

// ---------------- fused tail: logits = (relu(agg2 @ W2 + b2)) @ Wc + bc ------------
// (harness-verified round 7)

__global__ __launch_bounds__(256) void k_tail(const float* __restrict__ A,
                                              const float* __restrict__ B,
                                              const float* __restrict__ b2,
                                              const float* __restrict__ Wc,
                                              const float* __restrict__ bc,
                                              float* __restrict__ out,
                                              int M, int N, int K) {
  __shared__ float As[16][68];
  __shared__ float Bs[16][136];
  __shared__ float wsm[256];          // Wc: [N][2], N=128
  __shared__ float red[64][16][2];
  const int bm = blockIdx.x * 64;
  const int tid = threadIdx.x;
  const int tr = (tid >> 4) << 2;     // 0..60
  const int tc = (tid & 15) << 3;     // 0..120
  const int lm  = tid >> 2;           // A stage row 0..63
  const int lk  = (tid & 3) << 2;     // A stage k 0,4,8,12
  const int lk2 = tid >> 4;           // B stage k 0..15
  const int ln  = (tid & 15) << 3;    // B stage col 0..120
  wsm[tid] = Wc[tid];
  const bool arow_ok = (bm + lm) < M;
  const float* Aptr = A + (size_t)(bm + lm) * K + lk;
  const float* Bptr = B + (size_t)lk2 * N + ln;
  float acc[4][8] = {};
  for (int k0 = 0; k0 < K; k0 += 16) {
    float4 a4 = make_float4(0.f, 0.f, 0.f, 0.f);
    if (arow_ok) a4 = *(const float4*)(Aptr + k0);
    float4 b4 = *(const float4*)(Bptr + (size_t)k0 * N);
    float4 b5 = *(const float4*)(Bptr + (size_t)k0 * N + 4);
    As[lk + 0][lm] = a4.x;
    As[lk + 1][lm] = a4.y;
    As[lk + 2][lm] = a4.z;
    As[lk + 3][lm] = a4.w;
    *(float4*)&Bs[lk2][ln] = b4;
    *(float4*)&Bs[lk2][ln + 4] = b5;
    __syncthreads();
#pragma unroll
    for (int k = 0; k < 16; ++k) {
      float4 av = *(const float4*)&As[k][tr];
      float a[4] = {av.x, av.y, av.z, av.w};
      float b[8];
      *(float4*)&b[0] = *(const float4*)&Bs[k][tc];
      *(float4*)&b[4] = *(const float4*)&Bs[k][tc + 4];
#pragma unroll
      for (int i = 0; i < 4; ++i)
#pragma unroll
        for (int j = 0; j < 8; ++j) acc[i][j] += a[i] * b[j];
    }
    __syncthreads();
  }
  // relu + b2, then partial logits vs Wc
  float p[4][2] = {};
#pragma unroll
  for (int j = 0; j < 8; ++j) {
    float bb = b2[tc + j];
    float w0 = wsm[(tc + j) * 2 + 0];
    float w1 = wsm[(tc + j) * 2 + 1];
#pragma unroll
    for (int i = 0; i < 4; ++i) {
      float v = fmaxf(acc[i][j] + bb, 0.f);
      p[i][0] += v * w0;
      p[i][1] += v * w1;
    }
  }
#pragma unroll
  for (int i = 0; i < 4; ++i) {
    red[tr + i][tid & 15][0] = p[i][0];
    red[tr + i][tid & 15][1] = p[i][1];
  }
  __syncthreads();
  if (tid < 128) {
    int row = tid >> 1, kk = tid & 1;
    float s = 0.f;
#pragma unroll
    for (int t = 0; t < 16; ++t) s += red[row][t][kk];
    int r = bm + row;
    if (r < M) out[2 * r + kk] = s + bc[kk];
  }
}

// ---------------- launch ----------------

extern "C" void kernel_launch(void* const* d_in, const int* in_sizes, int n_in,
                              void* d_out, int out_size, void* d_ws, size_t ws_size,
                              hipStream_t stream) {
  const float* x   = (const float*)d_in[0];
  const int*   ei  = (const int*)d_in[1];
  const float* W1  = (const float*)d_in[2];
  const float* b1  = (const float*)d_in[3];
  const float* Wg1 = (const float*)d_in[4];
  const float* bg1 = (const float*)d_in[5];
  const float* Wg2 = (const float*)d_in[6];
  const float* bg2 = (const float*)d_in[7];
  const float* W2  = (const float*)d_in[8];
  const float* b2  = (const float*)d_in[9];
  const float* Wc  = (const float*)d_in[10];
  const float* bc  = (const float*)d_in[11];
  float* out = (float*)d_out;

  const int hid     = in_sizes[3];            // 256
  const int in_dim  = in_sizes[2] / hid;      // 768
  const int out_dim = in_sizes[9];            // 128
  const int N       = in_sizes[0] / in_dim;   // 50000
  const int E       = in_sizes[1] / 2;        // 800000
  const int Batch   = out_size / 2;           // 1024

  const int* srcI = ei;
  const int* dstI = ei + E;

  char* ws = (char*)d_ws;
  size_t off = 0;
  auto alloc = [&](size_t bytes) -> void* {
    void* p = ws + off;
    off = (off + bytes + 255) & ~(size_t)255;
    return p;
  };
  _Float16* h0h  = (_Float16*)alloc((size_t)N * hid * 2);
  _Float16* t1h  = (_Float16*)alloc((size_t)N * hid * 2);   // pre-scaled by dinv
  _Float16* h1h  = (_Float16*)alloc((size_t)N * hid * 2);   // only S1 rows valid
  _Float16* t2h  = (_Float16*)alloc((size_t)N * hid * 2);   // only S1 rows valid
  _Float16* W1t  = (_Float16*)alloc((size_t)in_dim * hid * 2);
  _Float16* Wg1t = (_Float16*)alloc((size_t)hid * hid * 2);
  _Float16* Wg2t = (_Float16*)alloc((size_t)hid * hid * 2);
  float* agg2    = (float*)alloc((size_t)Batch * hid * 4);
  float* dinv    = (float*)alloc((size_t)N * 4);
  int*   cnt     = (int*)alloc((size_t)N * 4);
  int*   rowp    = (int*)alloc((size_t)(N + 1) * 4);
  int*   fidx    = (int*)alloc((size_t)N * 4);
  int*   bsumc   = (int*)alloc((size_t)1024 * 4);
  int*   bsumf   = (int*)alloc((size_t)1024 * 4);
  int*   cursor  = (int*)alloc((size_t)N * 4);
  int*   csrs    = (int*)alloc((size_t)E * 4);
  int*   flag    = (int*)alloc((size_t)N * 4);
  int*   list    = (int*)alloc((size_t)N * 4);
  int*   s1cnt   = (int*)alloc((size_t)64);
  (void)ws_size; (void)n_in;

  dim3 blk(256);
  const int nb = (N + 1023) / 1024;

  // 1) zero + weight convert (fused)
  {
    int total = N + in_dim * hid + 2 * hid * hid;
    k_prep<<<(total + 255) / 256, blk, 0, stream>>>(cnt, flag, W1, Wg1, Wg2,
                                                    W1t, Wg1t, Wg2t, N, in_dim, hid);
  }
  // 2) count + S1 mark (fused E pass)
  k_countmark<<<(E + 255) / 256, blk, 0, stream>>>(srcI, dstI, cnt, flag, E, Batch);
  // 3-5) parallel dual scan + finalize/emit
  k_scan_local_dual<<<nb, 1024, 0, stream>>>(cnt, flag, rowp, fidx, bsumc, bsumf, N);
  k_scan_sums_dual<<<1, 1024, 0, stream>>>(bsumc, bsumf, nb);
  k_finalize_all<<<(N + 255) / 256, blk, 0, stream>>>(rowp, fidx, bsumc, bsumf, cnt, flag,
                                                      cursor, dinv, list, s1cnt, N, E);
  // 6) CSR fill
  k_fill<<<(E + 255) / 256, blk, 0, stream>>>(srcI, dstI, cursor, csrs, E);

  const int ng = (N + 255) / 256;   // 196 blocks, full-N output tile
  dim3 gblk(512);
  // 7) h0 = relu(x @ W1 + b1)
  k_gemm_mfma<float, 1, 1, 0, 0><<<dim3(ng), gblk, 0, stream>>>(x, W1t, b1, nullptr, h0h, N, hid, in_dim, nullptr, nullptr);
  // 8) t1' = (h0 @ Wg1) * dinv[row]   (all nodes)
  k_gemm_mfma<_Float16, 0, 0, 1, 0><<<dim3(ng), gblk, 0, stream>>>(h0h, Wg1t, nullptr, dinv, t1h, N, hid, hid, nullptr, nullptr);
  // 9) h1 = (t1'[i] + sum t1'[src]) * dinv[i] + bg1   -- S1 nodes only
  k_agg_g<<<(N + 3) / 4, blk, 0, stream>>>(t1h, rowp, csrs, dinv, bg1, h1h, list, s1cnt);
  // 10) t2' = (h1 @ Wg2) * dinv[row]   -- gather over S1 rows
  k_gemm_mfma<_Float16, 0, 0, 1, 1><<<dim3(ng), gblk, 0, stream>>>(h1h, Wg2t, nullptr, dinv, t2h, N, hid, hid, list, s1cnt);
  // 11) conv2 aggregation for rows [0, Batch) (fp32 out)
  k_agg<float><<<(Batch + 3) / 4, blk, 0, stream>>>(t2h, rowp, csrs, dinv, bg2, agg2, Batch);
  // 12) logits = relu(agg2 @ W2 + b2) @ Wc + bc   (fused tail)
  k_tail<<<(Batch + 63) / 64, blk, 0, stream>>>(agg2, W2, b2, Wc, bc, out, Batch, out_dim, hid);
}

// Round 9
// 484.128 us; speedup vs baseline: 1.5051x; 1.0800x over previous
//
#include <hip/hip_runtime.h>
#include <hip/hip_bf16.h>
#include <cstdint>
#include <cstddef>
#include <type_traits>

typedef _Float16 half8 __attribute__((ext_vector_type(8)));
typedef _Float16 half4v __attribute__((ext_vector_type(4)));
typedef float float4v __attribute__((ext_vector_type(4)));

// ---------------- fused prep: zero cnt/flag + weight convert/transpose ----------------

__global__ void k_prep(int* __restrict__ cnt, int* __restrict__ flag,
                       const float* __restrict__ W1, const float* __restrict__ Wg1,
                       const float* __restrict__ Wg2, _Float16* __restrict__ W1t,
                       _Float16* __restrict__ Wg1t, _Float16* __restrict__ Wg2t,
                       int n, int in_dim, int hid) {
  int idx = blockIdx.x * blockDim.x + threadIdx.x;
  if (idx < n) { cnt[idx] = 0; flag[idx] = 0; return; }
  int w = idx - n;
  int n1 = in_dim * hid;
  int n2 = hid * hid;
  if (w < n1) {
    int nn = w / in_dim, k = w - nn * in_dim;
    W1t[w] = (_Float16)W1[(size_t)k * hid + nn];
  } else if (w < n1 + n2) {
    int i2 = w - n1;
    int nn = i2 / hid, k = i2 - nn * hid;
    Wg1t[i2] = (_Float16)Wg1[(size_t)k * hid + nn];
  } else if (w < n1 + 2 * n2) {
    int i2 = w - n1 - n2;
    int nn = i2 / hid, k = i2 - nn * hid;
    Wg2t[i2] = (_Float16)Wg2[(size_t)k * hid + nn];
  }
}

// ---------------- fused count + S1 mark (one E pass) ----------------

__global__ void k_countmark(const int* __restrict__ src, const int* __restrict__ dst,
                            int* __restrict__ cnt, int* __restrict__ flag,
                            int E, int Batch) {
  int e = blockIdx.x * blockDim.x + threadIdx.x;
  if (e < E) {
    int d = dst[e];
    atomicAdd(&cnt[d], 1);
    if (d < Batch) flag[src[e]] = 1;
  }
  if (e < Batch) flag[e] = 1;
}

// ---------------- hierarchical DUAL scan (cnt & flag in one pass) -------------------
// (harness-verified round 8)

__global__ __launch_bounds__(1024) void k_scan_local_dual(const int* __restrict__ cnt,
                                                          const int* __restrict__ flag,
                                                          int* __restrict__ rowp,
                                                          int* __restrict__ fidx,
                                                          int* __restrict__ bsumc,
                                                          int* __restrict__ bsumf, int n) {
  __shared__ int smc[1024];
  __shared__ int smf[1024];
  int tid = threadIdx.x;
  int i = blockIdx.x * 1024 + tid;
  int vc = (i < n) ? cnt[i] : 0;
  int vf = (i < n) ? flag[i] : 0;
  smc[tid] = vc;
  smf[tid] = vf;
  __syncthreads();
  for (int off = 1; off < 1024; off <<= 1) {
    int tc_ = (tid >= off) ? smc[tid - off] : 0;
    int tf_ = (tid >= off) ? smf[tid - off] : 0;
    __syncthreads();
    smc[tid] += tc_;
    smf[tid] += tf_;
    __syncthreads();
  }
  if (i < n) {
    rowp[i] = smc[tid] - vc;  // exclusive (pre-fixup)
    fidx[i] = smf[tid] - vf;
  }
  if (tid == 1023) { bsumc[blockIdx.x] = smc[1023]; bsumf[blockIdx.x] = smf[1023]; }
}

__global__ __launch_bounds__(1024) void k_scan_sums_dual(int* __restrict__ bsumc,
                                                         int* __restrict__ bsumf, int nb) {
  __shared__ int smc[1024];
  __shared__ int smf[1024];
  int tid = threadIdx.x;
  int vc = (tid < nb) ? bsumc[tid] : 0;
  int vf = (tid < nb) ? bsumf[tid] : 0;
  smc[tid] = vc;
  smf[tid] = vf;
  __syncthreads();
  for (int off = 1; off < 1024; off <<= 1) {
    int tc_ = (tid >= off) ? smc[tid - off] : 0;
    int tf_ = (tid >= off) ? smf[tid - off] : 0;
    __syncthreads();
    smc[tid] += tc_;
    smf[tid] += tf_;
    __syncthreads();
  }
  if (tid < nb) { bsumc[tid] = smc[tid] - vc; bsumf[tid] = smf[tid] - vf; }
}

// fixup + cursor + dinv + S1 list emit + s1cnt + rowp[n], fused
__global__ void k_finalize_all(int* __restrict__ rowp, int* __restrict__ fidx,
                               const int* __restrict__ bsumc, const int* __restrict__ bsumf,
                               const int* __restrict__ cnt, const int* __restrict__ flag,
                               int* __restrict__ cursor, float* __restrict__ dinv,
                               int* __restrict__ list, int* __restrict__ s1cnt,
                               int n, int E) {
  int i = blockIdx.x * blockDim.x + threadIdx.x;
  if (i < n) {
    int v = rowp[i] + bsumc[i >> 10];
    rowp[i] = v;
    cursor[i] = v;
    dinv[i] = rsqrtf((float)(cnt[i] + 1));  // +1 self loop
    int f = flag[i];
    int fp = fidx[i] + bsumf[i >> 10];
    if (f) list[fp] = i;
    if (i == n - 1) { s1cnt[0] = fp + f; rowp[n] = E; }
  }
}

__global__ void k_fill(const int* __restrict__ src, const int* __restrict__ dst,
                       int* __restrict__ cursor, int* __restrict__ csr_src, int E) {
  int e = blockIdx.x * blockDim.x + threadIdx.x;
  if (e < E) {
    int pos = atomicAdd(&cursor[dst[e]], 1);
    csr_src[pos] = src[e];
  }
}

// ---------------- fp16 MFMA GEMM, 128x256 tile (full N), 2-buffer, 2 blocks/CU ------
// Round-8 post-mortem: 256x256/3-buf = 147KB LDS = 1 block/CU; per-CU staging stuck
// at ~11 GB/s and every barrier stalls the whole CU. Round 2 (3 blocks/CU) sustained
// ~1.7x the aggregate staging rate via cross-block overlap. This version keeps
// stage-A-once (BN=256=full N) but halves BM and drops to 2 buffers: 32KB/buf
// (fp32) -> 64KB LDS -> 2 blocks/CU; B re-staged per block is L2-resident (384KB).
// 8 waves, wave tile 64x64 (acc 4x4, ~100 VGPR -> 16 waves/CU). Loop: vmcnt(IPT)
// -> barrier -> compute kt -> barrier -> DMA tile kt+2 into the just-read buffer.
// fp32 A split-half layout (two 16-col half-buffers, 64B rows) as verified r3-r8.

__device__ __forceinline__ void gl_lds16(const void* g, void* l) {
  __builtin_amdgcn_global_load_lds(
      (const __attribute__((address_space(1))) void*)g,
      (__attribute__((address_space(3))) void*)l, 16, 0, 0);
}

#define VMCNT(n) asm volatile("s_waitcnt vmcnt(" #n ")" ::: "memory")

template <int RA>
__device__ __forceinline__ void dma_tile(const char* const (&aS)[RA], const int (&aD)[RA],
                                         const char* const (&bS)[2], const int (&bD)[2],
                                         char* ab, char* bb, size_t advA, size_t advB) {
#pragma unroll
  for (int rr = 0; rr < RA; ++rr) gl_lds16(aS[rr] + advA, ab + aD[rr]);
#pragma unroll
  for (int rr = 0; rr < 2; ++rr) gl_lds16(bS[rr] + advB, bb + bD[rr]);
}

template <typename AT, int RELU, int BIAS, int SCALE, int GATHER>
__global__ __launch_bounds__(512) void k_gemm_mfma(const AT* __restrict__ A,
                                                   const _Float16* __restrict__ Bt,
                                                   const float* __restrict__ bias,
                                                   const float* __restrict__ rowscale,
                                                   _Float16* __restrict__ out,
                                                   int M, int N, int K,
                                                   const int* __restrict__ ridx,
                                                   const int* __restrict__ rcnt) {
  __shared__ alignas(16) AT Asm[2][128 * 32];
  __shared__ alignas(16) _Float16 Bsm[2][256 * 32];
  constexpr bool AF32 = std::is_same_v<AT, float>;
  constexpr int RA = AF32 ? 2 : 1;                   // A DMA rounds (8KB each)
  constexpr int ABUFB = 128 * 32 * (int)sizeof(AT);  // 16KB / 8KB
  constexpr int BBUFB = 256 * 32 * 2;                // 16KB

  const int tid = threadIdx.x;
  const int wv = tid >> 6;          // 0..7
  const int ln = tid & 63;
  const int quad = ln >> 4;
  const int l15 = ln & 15;
  const int wm = (wv >> 2) * 64;    // 0 or 64
  const int wn = (wv & 3) * 64;     // 0,64,128,192

  const int bm = (int)blockIdx.x * 128;

  int Meff = M;
  if constexpr (GATHER) {
    Meff = rcnt[0];
    if (bm >= Meff) return;         // uniform per block, before any barrier
  }

  // ---- per-thread DMA source precompute (dest linear; source pre-permuted) ----
  const char* aSrcB[RA];
  int aDstOff[RA];
#pragma unroll
  for (int rr = 0; rr < RA; ++rr) {
    int q = rr * 8192 + wv * 1024 + ln * 16;  // byte pos in A buf
    int row, colE;                            // colE in elements
    if constexpr (AF32) {
      int h = q >> 13;                        // half-buffer (cols 0-15 | 16-31)
      int q13 = q & 8191;
      row = q13 >> 6;                         // 0..127 (64B rows)
      colE = ((q13 & 63) >> 2) + (h << 4);
    } else {
      row = q >> 6;                           // 0..127 (64B rows)
      colE = (q & 63) >> 1;
    }
    int li = bm + row; if (li > Meff - 1) li = Meff - 1;  // clamp; epilogue masks
    int grow;
    if constexpr (GATHER) grow = ridx[li]; else grow = li;
    aSrcB[rr] = (const char*)(A + (size_t)grow * K + colE);
    aDstOff[rr] = rr * 8192 + wv * 1024;      // wave-uniform (lane*16 added by HW)
  }
  const char* bSrcB[2];
  int bDstOff[2];
#pragma unroll
  for (int rr = 0; rr < 2; ++rr) {
    int q = rr * 8192 + wv * 1024 + ln * 16;  // byte pos in B buf
    int row = q >> 6;                         // 0..255
    int colH = (q & 63) >> 1;
    bSrcB[rr] = (const char*)(Bt + (size_t)row * K + colH);
    bDstOff[rr] = rr * 8192 + wv * 1024;
  }

  float4v acc[4][4];
#pragma unroll
  for (int i = 0; i < 4; ++i)
#pragma unroll
    for (int j = 0; j < 4; ++j) acc[i][j] = (float4v){0.f, 0.f, 0.f, 0.f};

  const int nk = K >> 5;   // >= 8 always here

  char* const Ab0 = (char*)&Asm[0][0];
  char* const Bb0 = (char*)&Bsm[0][0];

  // prologue: DMA tile 0 -> buf 0, tile 1 -> buf 1 (2*IPT outstanding)
  dma_tile<RA>(aSrcB, aDstOff, bSrcB, bDstOff, Ab0, Bb0, 0, 0);
  dma_tile<RA>(aSrcB, aDstOff, bSrcB, bDstOff, Ab0 + ABUFB, Bb0 + BBUFB,
               (size_t)32 * sizeof(AT), 64);

  int buf = 0;  // buffer holding tile kt (kt & 1)
  for (int kt = 0; kt < nk; ++kt) {
    // wait: tile kt resident (leave tile kt+1's IPT newest in flight)
    if (kt + 1 < nk) {
      if constexpr (AF32) { VMCNT(4); } else { VMCNT(3); }
    } else {
      VMCNT(0);
    }
    __builtin_amdgcn_sched_barrier(0);
    __builtin_amdgcn_s_barrier();       // publish all waves' tile-kt DMA
    __builtin_amdgcn_sched_barrier(0);

    // compute tile kt from buffer buf
    const AT* Ab = &Asm[buf][0];
    const _Float16* Bb = &Bsm[buf][0];
    half8 bf[4];
#pragma unroll
    for (int j = 0; j < 4; ++j)
      bf[j] = *(const half8*)(Bb + (wn + j * 16 + l15) * 32 + quad * 8);
#pragma unroll
    for (int i = 0; i < 4; ++i) {
      int rowa = wm + i * 16 + l15;
      half8 af;
      if constexpr (AF32) {
        // split-half: cols quad*8..quad*8+7 live in half (quad>>1), sub (quad&1)
        const float* ap = Ab + (quad >> 1) * 2048 + rowa * 16 + (quad & 1) * 8;
        float4v f0 = *(const float4v*)ap;
        float4v f1 = *(const float4v*)(ap + 4);
        af[0] = (_Float16)f0[0]; af[1] = (_Float16)f0[1];
        af[2] = (_Float16)f0[2]; af[3] = (_Float16)f0[3];
        af[4] = (_Float16)f1[0]; af[5] = (_Float16)f1[1];
        af[6] = (_Float16)f1[2]; af[7] = (_Float16)f1[3];
      } else {
        af = *(const half8*)(Ab + rowa * 32 + quad * 8);
      }
#pragma unroll
      for (int j = 0; j < 4; ++j)
        acc[i][j] = __builtin_amdgcn_mfma_f32_16x16x32_f16(af, bf[j], acc[i][j], 0, 0, 0);
    }

    __builtin_amdgcn_s_barrier();       // all reads of buf done before overwrite
    __builtin_amdgcn_sched_barrier(0);

    // issue tile kt+2 DMA into the buffer just read (kt+2 has same parity)
    if (kt + 2 < nk) {
      dma_tile<RA>(aSrcB, aDstOff, bSrcB, bDstOff,
                   Ab0 + (size_t)buf * ABUFB, Bb0 + (size_t)buf * BBUFB,
                   (size_t)(kt + 2) * 32 * sizeof(AT), (size_t)(kt + 2) * 64);
      __builtin_amdgcn_sched_barrier(0);
    }

    buf ^= 1;
  }

  // epilogue: C/D layout col=lane&15, row=quad*4+reg
#pragma unroll
  for (int j = 0; j < 4; ++j) {
    int c = wn + j * 16 + l15;
    float bv = BIAS ? bias[c] : 0.f;
#pragma unroll
    for (int i = 0; i < 4; ++i) {
      int rbase = bm + wm + i * 16 + quad * 4;
      float4v a = acc[i][j];
#pragma unroll
      for (int reg = 0; reg < 4; ++reg) {
        int r = rbase + reg;
        if (r < Meff) {
          int orow;
          if constexpr (GATHER) orow = ridx[r]; else orow = r;
          float v = a[reg] + bv;
          if (RELU) v = fmaxf(v, 0.f);
          if (SCALE) v *= rowscale[orow];
          out[(size_t)orow * N + c] = (_Float16)v;
        }
      }
    }
  }
}

// ---------------- GCN aggregation (gather, one wave/node, 256 feats) ----------------
// t is PRE-SCALED: t'[i] = t[i]*dinv[i].  out[i] = (t'[i] + sum t'[src]) * dinv[i] + b

template <typename OT>
__global__ __launch_bounds__(256) void k_agg(const _Float16* __restrict__ t,
                                             const int* __restrict__ row_ptr,
                                             const int* __restrict__ csr_src,
                                             const float* __restrict__ dinv,
                                             const float* __restrict__ bias,
                                             OT* __restrict__ out, int n_nodes) {
  int w = (int)((blockIdx.x * 256 + threadIdx.x) >> 6);
  int lane = threadIdx.x & 63;
  if (w >= n_nodes) return;
  float di = dinv[w];
  half4v v = *(const half4v*)(t + (size_t)w * 256 + lane * 4);
  float ax = (float)v[0], ay = (float)v[1], az = (float)v[2], aw = (float)v[3];
  int e0 = row_ptr[w], e1 = row_ptr[w + 1];
  int e = e0;
  for (; e + 4 <= e1; e += 4) {
    int s0 = csr_src[e];
    int s1 = csr_src[e + 1];
    int s2 = csr_src[e + 2];
    int s3 = csr_src[e + 3];
    half4v u0 = *(const half4v*)(t + (size_t)s0 * 256 + lane * 4);
    half4v u1 = *(const half4v*)(t + (size_t)s1 * 256 + lane * 4);
    half4v u2 = *(const half4v*)(t + (size_t)s2 * 256 + lane * 4);
    half4v u3 = *(const half4v*)(t + (size_t)s3 * 256 + lane * 4);
    ax += (float)u0[0] + (float)u1[0] + (float)u2[0] + (float)u3[0];
    ay += (float)u0[1] + (float)u1[1] + (float)u2[1] + (float)u3[1];
    az += (float)u0[2] + (float)u1[2] + (float)u2[2] + (float)u3[2];
    aw += (float)u0[3] + (float)u1[3] + (float)u2[3] + (float)u3[3];
  }
  for (; e < e1; ++e) {
    int s = csr_src[e];
    half4v u = *(const half4v*)(t + (size_t)s * 256 + lane * 4);
    ax += (float)u[0]; ay += (float)u[1]; az += (float)u[2]; aw += (float)u[3];
  }
  const float4 b = ((const float4*)bias)[lane];
  if constexpr (std::is_same_v<OT, float>) {
    float4 o;
    o.x = ax * di + b.x; o.y = ay * di + b.y;
    o.z = az * di + b.z; o.w = aw * di + b.w;
    ((float4*)(out + (size_t)w * 256))[lane] = o;
  } else {
    half4v o;
    o[0] = (_Float16)(ax * di + b.x); o[1] = (_Float16)(ay * di + b.y);
    o[2] = (_Float16)(az * di + b.z); o[3] = (_Float16)(aw * di + b.w);
    *(half4v*)(out + (size_t)w * 256 + lane * 4) = o;
  }
}

// list-driven variant: only nodes in list[0..s1cnt) are aggregated (S1 pruning).
__global__ __launch_bounds__(256) void k_agg_g(const _Float16* __restrict__ t,
                                               const int* __restrict__ row_ptr,
                                               const int* __restrict__ csr_src,
                                               const float* __restrict__ dinv,
                                               const float* __restrict__ bias,
                                               _Float16* __restrict__ out,
                                               const int* __restrict__ list,
                                               const int* __restrict__ s1cnt) {
  int wi = (int)((blockIdx.x * 256 + threadIdx.x) >> 6);
  int lane = threadIdx.x & 63;
  if (wi >= s1cnt[0]) return;      // per-wave uniform; no barriers in kernel
  int w = list[wi];
  float di = dinv[w];
  half4v v = *(const half4v*)(t + (size_t)w * 256 + lane * 4);
  float ax = (float)v[0], ay = (float)v[1], az = (float)v[2], aw = (float)v[3];
  int e0 = row_ptr[w], e1 = row_ptr[w + 1];
  int e = e0;
  for (; e + 4 <= e1; e += 4) {
    int s0 = csr_src[e];
    int s1 = csr_src[e + 1];
    int s2 = csr_src[e + 2];
    int s3 = csr_src[e + 3];
    half4v u0 = *(const half4v*)(t + (size_t)s0 * 256 + lane * 4);
    half4v u1 = *(const half4v*)(t + (size_t)s1 * 256 + lane * 4);
    half4v u2 = *(const half4v*)(t + (size_t)s2 * 256 + lane * 4);
    half4v u3 = *(const half4v*)(t + (size_t)s3 * 256 + lane * 4);
    ax += (float)u0[0] + (float)u1[0] + (float)u2[0] + (float)u3[0];
    ay += (float)u0[1] + (float)u1[1] + (float)u2[1] + (float)u3[1];
    az += (float)u0[2] + (float)u1[2] + (float)u2[2] + (float)u3[2];
    aw += (float)u0[3] + (float)u1[3] + (float)u2[3] + (float)u3[3];
  }
  for (; e < e1; ++e) {
    int s = csr_src[e];
    half4v u = *(const half4v*)(t + (size_t)s * 256 + lane * 4);
    ax += (float)u[0]; ay += (float)u[1]; az += (float)u[2]; aw += (float)u[3];
  }
  const float4 b = ((const float4*)bias)[lane];
  half4v o;
  o[0] = (_Float16)(ax * di + b.x); o[1] = (_Float16)(ay * di + b.y);
  o[2] = (_Float16)(az * di + b.z); o[3] = (_Float16)(aw * di + b.w);
  *(half4v*)(out + (size_t)w * 256 + lane * 4) = o;
}

// ---------------- fused tail: logits = (relu(agg2 @ W2 + b2)) @ Wc + bc ------------
// (harness-verified rounds 7/8)

__global__ __launch_bounds__(256) void k_tail(const float* __restrict__ A,
                                              const float* __restrict__ B,
                                              const float* __restrict__ b2,
                                              const float* __restrict__ Wc,
                                              const float* __restrict__ bc,
                                              float* __restrict__ out,
                                              int M, int N, int K) {
  __shared__ float As[16][68];
  __shared__ float Bs[16][136];
  __shared__ float wsm[256];          // Wc: [N][2], N=128
  __shared__ float red[64][16][2];
  const int bm = blockIdx.x * 64;
  const int tid = threadIdx.x;
  const int tr = (tid >> 4) << 2;     // 0..60
  const int tc = (tid & 15) << 3;     // 0..120
  const int lm  = tid >> 2;           // A stage row 0..63
  const int lk  = (tid & 3) << 2;     // A stage k 0,4,8,12
  const int lk2 = tid >> 4;           // B stage k 0..15
  const int ln  = (tid & 15) << 3;    // B stage col 0..120
  wsm[tid] = Wc[tid];
  const bool arow_ok = (bm + lm) < M;
  const float* Aptr = A + (size_t)(bm + lm) * K + lk;
  const float* Bptr = B + (size_t)lk2 * N + ln;
  float acc[4][8] = {};
  for (int k0 = 0; k0 < K; k0 += 16) {
    float4 a4 = make_float4(0.f, 0.f, 0.f, 0.f);
    if (arow_ok) a4 = *(const float4*)(Aptr + k0);
    float4 b4 = *(const float4*)(Bptr + (size_t)k0 * N);
    float4 b5 = *(const float4*)(Bptr + (size_t)k0 * N + 4);
    As[lk + 0][lm] = a4.x;
    As[lk + 1][lm] = a4.y;
    As[lk + 2][lm] = a4.z;
    As[lk + 3][lm] = a4.w;
    *(float4*)&Bs[lk2][ln] = b4;
    *(float4*)&Bs[lk2][ln + 4] = b5;
    __syncthreads();
#pragma unroll
    for (int k = 0; k < 16; ++k) {
      float4 av = *(const float4*)&As[k][tr];
      float a[4] = {av.x, av.y, av.z, av.w};
      float b[8];
      *(float4*)&b[0] = *(const float4*)&Bs[k][tc];
      *(float4*)&b[4] = *(const float4*)&Bs[k][tc + 4];
#pragma unroll
      for (int i = 0; i < 4; ++i)
#pragma unroll
        for (int j = 0; j < 8; ++j) acc[i][j] += a[i] * b[j];
    }
    __syncthreads();
  }
  // relu + b2, then partial logits vs Wc
  float p[4][2] = {};
#pragma unroll
  for (int j = 0; j < 8; ++j) {
    float bb = b2[tc + j];
    float w0 = wsm[(tc + j) * 2 + 0];
    float w1 = wsm[(tc + j) * 2 + 1];
#pragma unroll
    for (int i = 0; i < 4; ++i) {
      float v = fmaxf(acc[i][j] + bb, 0.f);
      p[i][0] += v * w0;
      p[i][1] += v * w1;
    }
  }
#pragma unroll
  for (int i = 0; i < 4; ++i) {
    red[tr + i][tid & 15][0] = p[i][0];
    red[tr + i][tid & 15][1] = p[i][1];
  }
  __syncthreads();
  if (tid < 128) {
    int row = tid >> 1, kk = tid & 1;
    float s = 0.f;
#pragma unroll
    for (int t = 0; t < 16; ++t) s += red[row][t][kk];
    int r = bm + row;
    if (r < M) out[2 * r + kk] = s + bc[kk];
  }
}

// ---------------- launch ----------------

extern "C" void kernel_launch(void* const* d_in, const int* in_sizes, int n_in,
                              void* d_out, int out_size, void* d_ws, size_t ws_size,
                              hipStream_t stream) {
  const float* x   = (const float*)d_in[0];
  const int*   ei  = (const int*)d_in[1];
  const float* W1  = (const float*)d_in[2];
  const float* b1  = (const float*)d_in[3];
  const float* Wg1 = (const float*)d_in[4];
  const float* bg1 = (const float*)d_in[5];
  const float* Wg2 = (const float*)d_in[6];
  const float* bg2 = (const float*)d_in[7];
  const float* W2  = (const float*)d_in[8];
  const float* b2  = (const float*)d_in[9];
  const float* Wc  = (const float*)d_in[10];
  const float* bc  = (const float*)d_in[11];
  float* out = (float*)d_out;

  const int hid     = in_sizes[3];            // 256
  const int in_dim  = in_sizes[2] / hid;      // 768
  const int out_dim = in_sizes[9];            // 128
  const int N       = in_sizes[0] / in_dim;   // 50000
  const int E       = in_sizes[1] / 2;        // 800000
  const int Batch   = out_size / 2;           // 1024

  const int* srcI = ei;
  const int* dstI = ei + E;

  char* ws = (char*)d_ws;
  size_t off = 0;
  auto alloc = [&](size_t bytes) -> void* {
    void* p = ws + off;
    off = (off + bytes + 255) & ~(size_t)255;
    return p;
  };
  _Float16* h0h  = (_Float16*)alloc((size_t)N * hid * 2);
  _Float16* t1h  = (_Float16*)alloc((size_t)N * hid * 2);   // pre-scaled by dinv
  _Float16* h1h  = (_Float16*)alloc((size_t)N * hid * 2);   // only S1 rows valid
  _Float16* t2h  = (_Float16*)alloc((size_t)N * hid * 2);   // only S1 rows valid
  _Float16* W1t  = (_Float16*)alloc((size_t)in_dim * hid * 2);
  _Float16* Wg1t = (_Float16*)alloc((size_t)hid * hid * 2);
  _Float16* Wg2t = (_Float16*)alloc((size_t)hid * hid * 2);
  float* agg2    = (float*)alloc((size_t)Batch * hid * 4);
  float* dinv    = (float*)alloc((size_t)N * 4);
  int*   cnt     = (int*)alloc((size_t)N * 4);
  int*   rowp    = (int*)alloc((size_t)(N + 1) * 4);
  int*   fidx    = (int*)alloc((size_t)N * 4);
  int*   bsumc   = (int*)alloc((size_t)1024 * 4);
  int*   bsumf   = (int*)alloc((size_t)1024 * 4);
  int*   cursor  = (int*)alloc((size_t)N * 4);
  int*   csrs    = (int*)alloc((size_t)E * 4);
  int*   flag    = (int*)alloc((size_t)N * 4);
  int*   list    = (int*)alloc((size_t)N * 4);
  int*   s1cnt   = (int*)alloc((size_t)64);
  (void)ws_size; (void)n_in;

  dim3 blk(256);
  const int nb = (N + 1023) / 1024;

  // 1) zero + weight convert (fused)
  {
    int total = N + in_dim * hid + 2 * hid * hid;
    k_prep<<<(total + 255) / 256, blk, 0, stream>>>(cnt, flag, W1, Wg1, Wg2,
                                                    W1t, Wg1t, Wg2t, N, in_dim, hid);
  }
  // 2) count + S1 mark (fused E pass)
  k_countmark<<<(E + 255) / 256, blk, 0, stream>>>(srcI, dstI, cnt, flag, E, Batch);
  // 3-5) parallel dual scan + finalize/emit
  k_scan_local_dual<<<nb, 1024, 0, stream>>>(cnt, flag, rowp, fidx, bsumc, bsumf, N);
  k_scan_sums_dual<<<1, 1024, 0, stream>>>(bsumc, bsumf, nb);
  k_finalize_all<<<(N + 255) / 256, blk, 0, stream>>>(rowp, fidx, bsumc, bsumf, cnt, flag,
                                                      cursor, dinv, list, s1cnt, N, E);
  // 6) CSR fill
  k_fill<<<(E + 255) / 256, blk, 0, stream>>>(srcI, dstI, cursor, csrs, E);

  const int ng = (N + 127) / 128;   // 391 blocks, full-N output tile, 2 blocks/CU
  dim3 gblk(512);
  // 7) h0 = relu(x @ W1 + b1)
  k_gemm_mfma<float, 1, 1, 0, 0><<<dim3(ng), gblk, 0, stream>>>(x, W1t, b1, nullptr, h0h, N, hid, in_dim, nullptr, nullptr);
  // 8) t1' = (h0 @ Wg1) * dinv[row]   (all nodes)
  k_gemm_mfma<_Float16, 0, 0, 1, 0><<<dim3(ng), gblk, 0, stream>>>(h0h, Wg1t, nullptr, dinv, t1h, N, hid, hid, nullptr, nullptr);
  // 9) h1 = (t1'[i] + sum t1'[src]) * dinv[i] + bg1   -- S1 nodes only
  k_agg_g<<<(N + 3) / 4, blk, 0, stream>>>(t1h, rowp, csrs, dinv, bg1, h1h, list, s1cnt);
  // 10) t2' = (h1 @ Wg2) * dinv[row]   -- gather over S1 rows
  k_gemm_mfma<_Float16, 0, 0, 1, 1><<<dim3(ng), gblk, 0, stream>>>(h1h, Wg2t, nullptr, dinv, t2h, N, hid, hid, list, s1cnt);
  // 11) conv2 aggregation for rows [0, Batch) (fp32 out)
  k_agg<float><<<(Batch + 3) / 4, blk, 0, stream>>>(t2h, rowp, csrs, dinv, bg2, agg2, Batch);
  // 12) logits = relu(agg2 @ W2 + b2) @ Wc + bc   (fused tail)
  k_tail<<<(Batch + 63) / 64, blk, 0, stream>>>(agg2, W2, b2, Wc, bc, out, Batch, out_dim, hid);
}